// Round 4
// baseline (251.665 us; speedup 1.0000x reference)
//
#include <hip/hip_runtime.h>
#include <hip/hip_bf16.h>
#include <stdint.h>

typedef __bf16 bf16_t;
typedef __bf16 bf16x8 __attribute__((ext_vector_type(8)));
typedef float f32x4 __attribute__((ext_vector_type(4)));

#define HEADS 8
#define ATTD 32
#define NBATCH 8
#define SEQ 2048
#define DIN 256
#define WDIM 256
#define MTOT (NBATCH*SEQ)          // 16384
#define HBSZ ((size_t)MTOT*WDIM)   // 4.19M elems: size of ONE split-head tensor [64][2048][32]
// (1/sqrt(32)) * log2(e)
#define SCALE_L2E 0.25503322964704155f

// ---------------- f32 -> bf16 convert (n % 1024 == 0) ----------------
__global__ __launch_bounds__(256) void cvt_kernel(const float* __restrict__ src,
                                                  bf16_t* __restrict__ dst) {
    int i = (blockIdx.x * 256 + threadIdx.x) * 4;
    float4 v = *(const float4*)(src + i);
    union { bf16_t h[4]; uint2 u; } t;
    t.h[0] = (bf16_t)v.x; t.h[1] = (bf16_t)v.y;
    t.h[2] = (bf16_t)v.z; t.h[3] = (bf16_t)v.w;
    *(uint2*)(dst + i) = t.u;
}

// ---------------- GEMM: out[m,o] = X[m,:] . W[o,:] + bias[o] ----------------
// X: [MTOT, 256] bf16 row-major. W: [256, 256] bf16 row-major (torch Linear layout).
// MODE 0: out bf16 split-head [(o>>5)*MTOT + m][o&31], tensor z at outbase + z*HBSZ
// MODE 1: out f32 plain [m][o]
template<int MODE>
__global__ __launch_bounds__(256) void gemm_kernel(
    const bf16_t* __restrict__ Xall, const bf16_t* __restrict__ Wall,
    const float* __restrict__ b0, const float* __restrict__ b1,
    const float* __restrict__ b2, void* __restrict__ outbase)
{
    __shared__ bf16_t As[128*64];
    __shared__ bf16_t Bs[128*64];

    const int tid = threadIdx.x;
    const int z   = blockIdx.z;
    const int m0  = blockIdx.y * 128;
    const int n0  = blockIdx.x * 128;
    const bf16_t* A  = Xall + (size_t)z * MTOT * DIN;
    const bf16_t* Bw = Wall + (size_t)z * WDIM * DIN;
    const float* bias = (z == 0) ? b0 : (z == 1) ? b1 : b2;

    const int wv = tid >> 6, ln = tid & 63, g = ln >> 4, l15 = ln & 15;
    const int wm = wv >> 1, wn = wv & 1;

    f32x4 acc[4][4];
#pragma unroll
    for (int i = 0; i < 4; ++i)
#pragma unroll
        for (int j = 0; j < 4; ++j) acc[i][j] = (f32x4){0.f,0.f,0.f,0.f};

    for (int kt = 0; kt < DIN/64; ++kt) {
        if (kt) __syncthreads();
        // register staging: 1024 chunks of 8 bf16 per matrix, 4 per thread
#pragma unroll
        for (int iss = 0; iss < 4; ++iss) {
            int chunk = iss*256 + tid;
            bf16x8 av = *(const bf16x8*)(A  + (size_t)(m0 + (chunk>>3))*DIN + kt*64 + (chunk&7)*8);
            bf16x8 bv = *(const bf16x8*)(Bw + (size_t)(n0 + (chunk>>3))*DIN + kt*64 + (chunk&7)*8);
            *(bf16x8*)(As + chunk*8) = av;
            *(bf16x8*)(Bs + chunk*8) = bv;
        }
        __syncthreads();
#pragma unroll
        for (int kk = 0; kk < 2; ++kk) {
            bf16x8 af[4], bfr[4];
#pragma unroll
            for (int i = 0; i < 4; ++i)
                af[i] = *(const bf16x8*)(As + (wm*64 + i*16 + l15)*64 + kk*32 + g*8);
#pragma unroll
            for (int j = 0; j < 4; ++j)
                bfr[j] = *(const bf16x8*)(Bs + (wn*64 + j*16 + l15)*64 + kk*32 + g*8);
#pragma unroll
            for (int i = 0; i < 4; ++i)
#pragma unroll
                for (int j = 0; j < 4; ++j)
                    acc[i][j] = __builtin_amdgcn_mfma_f32_16x16x32_bf16(
                        af[i], bfr[j], acc[i][j], 0, 0, 0);
        }
    }

    // epilogue: C/D layout col = l15, row = g*4 + r
#pragma unroll
    for (int i = 0; i < 4; ++i) {
        int m = m0 + wm*64 + i*16 + g*4;
#pragma unroll
        for (int j = 0; j < 4; ++j) {
            int o = n0 + wn*64 + j*16 + l15;
            float bb = bias[o];
#pragma unroll
            for (int r = 0; r < 4; ++r) {
                float val = acc[i][j][r] + bb;
                if (MODE == 0) {
                    bf16_t* out = (bf16_t*)outbase + (size_t)z * HBSZ;
                    out[((size_t)(o >> 5) * MTOT + (m + r)) * ATTD + (o & 31)] = (bf16_t)val;
                } else {
                    ((float*)outbase)[(size_t)(m + r) * WDIM + o] = val;
                }
            }
        }
    }
}

// ---------------- flash attention ----------------
// Qh/Kh/Vh: [64][2048][32] bf16  (bh = h*8 + b)
// ATTo: [b][n][h*32+d] bf16  (recombined layout for the output projection)
__global__ __launch_bounds__(256) void attn_kernel(
    const bf16_t* __restrict__ Qh, const bf16_t* __restrict__ Kh,
    const bf16_t* __restrict__ Vh, bf16_t* __restrict__ ATTo)
{
    __shared__ bf16_t Ks[64*40];      // K tile, row stride 40 (pad vs 32)
    __shared__ bf16_t Vts[32*72];     // V tile transposed [d][kv], stride 72
    __shared__ bf16_t Ps[4][16*72];   // per-wave P buffer [q][kv], stride 72

    const int qt = 31 - blockIdx.x;   // long blocks dispatched first
    const int bh = blockIdx.y;
    const int hh = bh >> 3, bb = bh & 7;
    const int tid = threadIdx.x;
    const int wv = tid >> 6, ln = tid & 63, g = ln >> 4, l15 = ln & 15;
    const int n0 = qt * 64;

    // Q fragment (A operand): row = l15, k = g*8 + j ; d = 32 = one MFMA K
    bf16x8 qfrag = *(const bf16x8*)(Qh + ((size_t)bh*SEQ + n0 + wv*16 + l15)*ATTD + g*8);

    f32x4 o0 = {0.f,0.f,0.f,0.f}, o1 = {0.f,0.f,0.f,0.f};
    float mrow[4], lrow[4];
#pragma unroll
    for (int r = 0; r < 4; ++r) { mrow[r] = -1e30f; lrow[r] = 0.f; }

    const int kr = tid >> 2, kc = (tid & 3) * 8;   // K staging: 4 thr/row
    const int vr = tid & 63, vc = (tid >> 6) * 8;  // V staging: col-slab per wave

    const f32x4 zero4 = {0.f,0.f,0.f,0.f};

    for (int j = 0; j <= qt; ++j) {
        if (j) __syncthreads();
        // stage K [64][32] -> Ks
        bf16x8 kv8 = *(const bf16x8*)(Kh + ((size_t)bh*SEQ + j*64 + kr)*ATTD + kc);
        *(bf16x8*)(&Ks[kr*40 + kc]) = kv8;
        // stage V transposed -> Vts[d][kv]
        bf16x8 vv8 = *(const bf16x8*)(Vh + ((size_t)bh*SEQ + j*64 + vr)*ATTD + vc);
#pragma unroll
        for (int e = 0; e < 8; ++e) Vts[(vc + e)*72 + vr] = vv8[e];
        __syncthreads();

        // S = Q K^T : D col = kv (l15), row = q (g*4+r)
        f32x4 s[4];
#pragma unroll
        for (int c = 0; c < 4; ++c) {
            bf16x8 kf = *(const bf16x8*)(&Ks[(c*16 + l15)*40 + g*8]);
            s[c] = __builtin_amdgcn_mfma_f32_16x16x32_bf16(qfrag, kf, zero4, 0, 0, 0);
        }
        if (j == qt) {   // causal mask within diagonal tile
#pragma unroll
            for (int c = 0; c < 4; ++c)
#pragma unroll
                for (int r = 0; r < 4; ++r) {
                    int ql = wv*16 + g*4 + r, kl = c*16 + l15;
                    if (kl > ql) s[c][r] = -1e30f;
                }
        }
        // row max (16-lane butterfly; xor offsets 1/2/4/8 stay within same-g group)
        float tmax[4];
#pragma unroll
        for (int r = 0; r < 4; ++r)
            tmax[r] = fmaxf(fmaxf(s[0][r], s[1][r]), fmaxf(s[2][r], s[3][r]));
#pragma unroll
        for (int st = 0; st < 4; ++st) {
            int off = 1 << st;
#pragma unroll
            for (int r = 0; r < 4; ++r)
                tmax[r] = fmaxf(tmax[r], __shfl_xor(tmax[r], off));
        }
        float alpha[4], rsum[4];
#pragma unroll
        for (int r = 0; r < 4; ++r) {
            float mnew = fmaxf(mrow[r], tmax[r]);
            alpha[r] = exp2f((mrow[r] - mnew) * SCALE_L2E);
            mrow[r] = mnew;
            rsum[r] = 0.f;
        }
        // P = exp2((s-m)*c), stash to per-wave LDS in A-operand layout
#pragma unroll
        for (int c = 0; c < 4; ++c)
#pragma unroll
            for (int r = 0; r < 4; ++r) {
                float p = exp2f((s[c][r] - mrow[r]) * SCALE_L2E);
                rsum[r] += p;
                Ps[wv][(g*4 + r)*72 + c*16 + l15] = (bf16_t)p;
            }
#pragma unroll
        for (int st = 0; st < 4; ++st) {
            int off = 1 << st;
#pragma unroll
            for (int r = 0; r < 4; ++r)
                rsum[r] += __shfl_xor(rsum[r], off);
        }
#pragma unroll
        for (int r = 0; r < 4; ++r) {
            lrow[r] = lrow[r]*alpha[r] + rsum[r];
            o0[r] *= alpha[r];
            o1[r] *= alpha[r];
        }
        // fence: order the Ps scalar writes before the vector re-reads
        __syncthreads();
        // PV: A = P (row=q l15, k=kv), B = Vt rows are d
        bf16x8 pa0 = *(const bf16x8*)(&Ps[wv][l15*72 + g*8]);
        bf16x8 pa1 = *(const bf16x8*)(&Ps[wv][l15*72 + 32 + g*8]);
        bf16x8 vf;
        vf = *(const bf16x8*)(&Vts[(l15)*72 + g*8]);
        o0 = __builtin_amdgcn_mfma_f32_16x16x32_bf16(pa0, vf, o0, 0, 0, 0);
        vf = *(const bf16x8*)(&Vts[(l15)*72 + 32 + g*8]);
        o0 = __builtin_amdgcn_mfma_f32_16x16x32_bf16(pa1, vf, o0, 0, 0, 0);
        vf = *(const bf16x8*)(&Vts[(16 + l15)*72 + g*8]);
        o1 = __builtin_amdgcn_mfma_f32_16x16x32_bf16(pa0, vf, o1, 0, 0, 0);
        vf = *(const bf16x8*)(&Vts[(16 + l15)*72 + 32 + g*8]);
        o1 = __builtin_amdgcn_mfma_f32_16x16x32_bf16(pa1, vf, o1, 0, 0, 0);
    }

    // epilogue: divide by l, write recombined [b][n][h*32+d]
#pragma unroll
    for (int r = 0; r < 4; ++r) {
        float inv = 1.0f / lrow[r];
        int n = n0 + wv*16 + g*4 + r;
        size_t base = ((size_t)bb*SEQ + n)*WDIM + hh*ATTD;
        ATTo[base + l15]      = (bf16_t)(o0[r] * inv);
        ATTo[base + 16 + l15] = (bf16_t)(o1[r] * inv);
    }
}

// ---------------- launch ----------------
extern "C" void kernel_launch(void* const* d_in, const int* in_sizes, int n_in,
                              void* d_out, int out_size, void* d_ws, size_t ws_size,
                              hipStream_t stream) {
    const float* q_in = (const float*)d_in[0];
    const float* k_in = (const float*)d_in[1];
    const float* v_in = (const float*)d_in[2];
    const float* Wq = (const float*)d_in[3];
    const float* bq = (const float*)d_in[4];
    const float* Wk = (const float*)d_in[5];
    const float* bk = (const float*)d_in[6];
    const float* Wv = (const float*)d_in[7];
    const float* bv = (const float*)d_in[8];
    const float* Wo = (const float*)d_in[9];
    const float* bo = (const float*)d_in[10];

    char* p = (char*)d_ws;
    bf16_t* Xbf  = (bf16_t*)p; p += (size_t)3*MTOT*DIN*2;   // 25.2 MB
    bf16_t* Wbf  = (bf16_t*)p; p += (size_t)4*WDIM*DIN*2;   // 0.5 MB
    bf16_t* QKVh = (bf16_t*)p; p += 3*HBSZ*2;               // 25.2 MB (FIXED: was 8x too small)
    bf16_t* ATTo = (bf16_t*)d_ws;  // aliases Xbf (dead after QKV GEMM), needs 8.4 MB

    cvt_kernel<<<dim3(MTOT*DIN/1024), 256, 0, stream>>>(q_in, Xbf);
    cvt_kernel<<<dim3(MTOT*DIN/1024), 256, 0, stream>>>(k_in, Xbf + (size_t)MTOT*DIN);
    cvt_kernel<<<dim3(MTOT*DIN/1024), 256, 0, stream>>>(v_in, Xbf + (size_t)2*MTOT*DIN);
    cvt_kernel<<<dim3(WDIM*DIN/1024), 256, 0, stream>>>(Wq, Wbf);
    cvt_kernel<<<dim3(WDIM*DIN/1024), 256, 0, stream>>>(Wk, Wbf + 1*WDIM*DIN);
    cvt_kernel<<<dim3(WDIM*DIN/1024), 256, 0, stream>>>(Wv, Wbf + 2*WDIM*DIN);
    cvt_kernel<<<dim3(WDIM*DIN/1024), 256, 0, stream>>>(Wo, Wbf + 3*WDIM*DIN);

    gemm_kernel<0><<<dim3(2,128,3), 256, 0, stream>>>(Xbf, Wbf, bq, bk, bv, QKVh);
    attn_kernel<<<dim3(32,64), 256, 0, stream>>>(QKVh,
                                                 QKVh + HBSZ,
                                                 QKVh + 2*HBSZ, ATTo);
    gemm_kernel<1><<<dim3(2,128,1), 256, 0, stream>>>(ATTo, Wbf + 3*WDIM*DIN,
                                                      bo, bo, bo, d_out);
}

// Round 5
// 110.673 us; speedup vs baseline: 2.2740x; 2.2740x over previous
//
#include <hip/hip_runtime.h>
#include <hip/hip_bf16.h>
#include <stdint.h>

typedef __bf16 bf16_t;
typedef __bf16 bf16x4 __attribute__((ext_vector_type(4)));
typedef __bf16 bf16x8 __attribute__((ext_vector_type(8)));
typedef float f32x4 __attribute__((ext_vector_type(4)));

#define HEADS 8
#define ATTD 32
#define NBATCH 8
#define SEQ 2048
#define DIN 256
#define WDIM 256
#define MTOT (NBATCH*SEQ)          // 16384
#define HBSZ ((size_t)MTOT*WDIM)   // elems of ONE split-head tensor [64][2048][32]
// (1/sqrt(32)) * log2(e) — folded into Q during the QKV GEMM epilogue
#define SCALE_L2E 0.25503322964704155f

// ---------------- GEMM: out[m,o] = X[m,:] . W[o,:] + bias[o] ----------------
// MODE 0: X = f32 (q/k/v inputs, selected by z), W = f32; out bf16 split-head
//         [(o>>5)*MTOT + m][o&31] at outbase + z*HBSZ; z==0 scaled by SCALE_L2E.
// MODE 1: X = bf16 (ATTo), W = f32 (Wo); out f32 plain [m][o]
template<int MODE>
__global__ __launch_bounds__(256) void gemm_kernel(
    const void* __restrict__ X0, const void* __restrict__ X1,
    const void* __restrict__ X2,
    const float* __restrict__ W0, const float* __restrict__ W1,
    const float* __restrict__ W2,
    const float* __restrict__ b0, const float* __restrict__ b1,
    const float* __restrict__ b2, void* __restrict__ outbase)
{
    __shared__ bf16_t As[128*64];
    __shared__ bf16_t Bs[128*64];

    const int tid = threadIdx.x;
    const int z   = blockIdx.z;
    const int m0  = blockIdx.y * 128;
    const int n0  = blockIdx.x * 128;
    const void*  Xin  = (z == 0) ? X0 : (z == 1) ? X1 : X2;
    const float* Wf   = (z == 0) ? W0 : (z == 1) ? W1 : W2;
    const float* bias = (z == 0) ? b0 : (z == 1) ? b1 : b2;

    const int wv = tid >> 6, ln = tid & 63, g = ln >> 4, l15 = ln & 15;
    const int wm = wv >> 1, wn = wv & 1;

    f32x4 acc[4][4];
#pragma unroll
    for (int i = 0; i < 4; ++i)
#pragma unroll
        for (int j = 0; j < 4; ++j) acc[i][j] = (f32x4){0.f,0.f,0.f,0.f};

    for (int kt = 0; kt < DIN/64; ++kt) {
        if (kt) __syncthreads();
#pragma unroll
        for (int iss = 0; iss < 4; ++iss) {
            int chunk = iss*256 + tid;
            int row = chunk >> 3, c8 = (chunk & 7) * 8;
            union { bf16_t h[8]; bf16x8 v; } av, bvv;
            if (MODE == 0) {
                const float* A = (const float*)Xin;
                float4 a0 = *(const float4*)(A + (size_t)(m0+row)*DIN + kt*64 + c8);
                float4 a1 = *(const float4*)(A + (size_t)(m0+row)*DIN + kt*64 + c8 + 4);
                av.h[0]=(bf16_t)a0.x; av.h[1]=(bf16_t)a0.y; av.h[2]=(bf16_t)a0.z; av.h[3]=(bf16_t)a0.w;
                av.h[4]=(bf16_t)a1.x; av.h[5]=(bf16_t)a1.y; av.h[6]=(bf16_t)a1.z; av.h[7]=(bf16_t)a1.w;
            } else {
                av.v = *(const bf16x8*)((const bf16_t*)Xin + (size_t)(m0+row)*DIN + kt*64 + c8);
            }
            float4 w0 = *(const float4*)(Wf + (size_t)(n0+row)*DIN + kt*64 + c8);
            float4 w1 = *(const float4*)(Wf + (size_t)(n0+row)*DIN + kt*64 + c8 + 4);
            bvv.h[0]=(bf16_t)w0.x; bvv.h[1]=(bf16_t)w0.y; bvv.h[2]=(bf16_t)w0.z; bvv.h[3]=(bf16_t)w0.w;
            bvv.h[4]=(bf16_t)w1.x; bvv.h[5]=(bf16_t)w1.y; bvv.h[6]=(bf16_t)w1.z; bvv.h[7]=(bf16_t)w1.w;
            *(bf16x8*)(As + chunk*8) = av.v;
            *(bf16x8*)(Bs + chunk*8) = bvv.v;
        }
        __syncthreads();
#pragma unroll
        for (int kk = 0; kk < 2; ++kk) {
            bf16x8 af[4], bfr[4];
#pragma unroll
            for (int i = 0; i < 4; ++i)
                af[i] = *(const bf16x8*)(As + (wm*64 + i*16 + l15)*64 + kk*32 + g*8);
#pragma unroll
            for (int j = 0; j < 4; ++j)
                bfr[j] = *(const bf16x8*)(Bs + (wn*64 + j*16 + l15)*64 + kk*32 + g*8);
#pragma unroll
            for (int i = 0; i < 4; ++i)
#pragma unroll
                for (int j = 0; j < 4; ++j)
                    acc[i][j] = __builtin_amdgcn_mfma_f32_16x16x32_bf16(
                        af[i], bfr[j], acc[i][j], 0, 0, 0);
        }
    }

    // epilogue: C/D layout col = l15, row = g*4 + r
#pragma unroll
    for (int i = 0; i < 4; ++i) {
        int m = m0 + wm*64 + i*16 + g*4;
#pragma unroll
        for (int j = 0; j < 4; ++j) {
            int o = n0 + wn*64 + j*16 + l15;
            float bb = bias[o];
#pragma unroll
            for (int r = 0; r < 4; ++r) {
                float val = acc[i][j][r] + bb;
                if (MODE == 0) {
                    if (z == 0) val *= SCALE_L2E;   // fold softmax scale into Q
                    bf16_t* out = (bf16_t*)outbase + (size_t)z * HBSZ;
                    out[((size_t)(o >> 5) * MTOT + (m + r)) * ATTD + (o & 31)] = (bf16_t)val;
                } else {
                    ((float*)outbase)[(size_t)(m + r) * WDIM + o] = val;
                }
            }
        }
    }
}

// ---------------- flash attention (swapped QK^T, in-register softmax) -------
// Qh/Kh/Vh: [64][2048][32] bf16 (bh = h*8 + b); Q pre-scaled by SCALE_L2E.
// ATTo: [b][n][h*32+d] bf16.
// Each block: 2 q-tiles {qtx, 31-qtx} of 64 rows (uniform 33 kv-tiles total).
// Wave wv owns q rows wv*16..wv*16+15; lane (l15,g): q = l15 (one row/lane).
__global__ __launch_bounds__(256) void attn_kernel(
    const bf16_t* __restrict__ Qh, const bf16_t* __restrict__ Kh,
    const bf16_t* __restrict__ Vh, bf16_t* __restrict__ ATTo)
{
    __shared__ bf16_t Ks[2][64*40];    // K tile [kv][d], row stride 40
    __shared__ bf16_t Vts[2][32*72];   // V^T tile [d][kv], row stride 72

    const int qtx = blockIdx.x;
    const int bh  = blockIdx.y;
    const int hh = bh >> 3, bb = bh & 7;
    const int tid = threadIdx.x;
    const int wv = tid >> 6, ln = tid & 63, g = ln >> 4, l15 = ln & 15;

    const int kr = tid >> 2, kc = (tid & 3) * 8;   // K staging: 4 thr/row
    const int vr = ln, vc = wv * 8;                // V staging: d-slab per wave
    const f32x4 zero4 = {0.f,0.f,0.f,0.f};
    const size_t bhs = (size_t)bh * SEQ;

    for (int half = 0; half < 2; ++half) {
        const int qt = half ? (31 - qtx) : qtx;
        const int n0 = qt * 64;
        const bf16x8 qfrag = *(const bf16x8*)(Qh + (bhs + n0 + wv*16 + l15)*ATTD + g*8);
        f32x4 o0 = zero4, o1 = zero4;
        float m = -1e30f, l = 0.f;

        // prologue: stage tile 0 into buf0
        bf16x8 kreg = *(const bf16x8*)(Kh + (bhs + kr)*ATTD + kc);
        bf16x8 vreg = *(const bf16x8*)(Vh + (bhs + vr)*ATTD + vc);
        __syncthreads();   // previous half's readers done with LDS
        *(bf16x8*)(&Ks[0][kr*40 + kc]) = kreg;
#pragma unroll
        for (int e = 0; e < 8; ++e) Vts[0][(vc+e)*72 + vr] = vreg[e];

        for (int j = 0; j <= qt; ++j) {
            const int cur = j & 1;
            // issue next tile's loads early (clamped reload on last iter)
            const int jn = (j < qt) ? (j + 1) : j;
            kreg = *(const bf16x8*)(Kh + (bhs + jn*64 + kr)*ATTD + kc);
            vreg = *(const bf16x8*)(Vh + (bhs + jn*64 + vr)*ATTD + vc);
            __syncthreads();   // buf[cur] fully staged; prev buf reads done

            // S^T = K·Q^T : lane (l15,g) gets q=l15, kv = c*16 + g*4 + r
            f32x4 s[4];
#pragma unroll
            for (int c = 0; c < 4; ++c) {
                bf16x8 kf = *(const bf16x8*)(&Ks[cur][(c*16 + l15)*40 + g*8]);
                s[c] = __builtin_amdgcn_mfma_f32_16x16x32_bf16(kf, qfrag, zero4, 0, 0, 0);
            }
            if (j == qt) {   // causal mask on diagonal tile
                const int ql = wv*16 + l15;
#pragma unroll
                for (int c = 0; c < 4; ++c)
#pragma unroll
                    for (int r = 0; r < 4; ++r)
                        if (c*16 + g*4 + r > ql) s[c][r] = -1e30f;
            }
            // in-register softmax for row q=l15: 16 own values + 2 shuffles
            float pmax = fmaxf(
                fmaxf(fmaxf(fmaxf(s[0][0],s[0][1]), fmaxf(s[0][2],s[0][3])),
                      fmaxf(fmaxf(s[1][0],s[1][1]), fmaxf(s[1][2],s[1][3]))),
                fmaxf(fmaxf(fmaxf(s[2][0],s[2][1]), fmaxf(s[2][2],s[2][3])),
                      fmaxf(fmaxf(s[3][0],s[3][1]), fmaxf(s[3][2],s[3][3]))));
            pmax = fmaxf(pmax, __shfl_xor(pmax, 16));
            pmax = fmaxf(pmax, __shfl_xor(pmax, 32));
            const float mnew = fmaxf(m, pmax);
            const float alpha = exp2f(m - mnew);
            m = mnew;
            float p[4][4];
            float rsum = 0.f;
#pragma unroll
            for (int c = 0; c < 4; ++c)
#pragma unroll
                for (int r = 0; r < 4; ++r) {
                    p[c][r] = exp2f(s[c][r] - mnew);
                    rsum += p[c][r];
                }
            rsum += __shfl_xor(rsum, 16);
            rsum += __shfl_xor(rsum, 32);
            l = l*alpha + rsum;
#pragma unroll
            for (int r = 0; r < 4; ++r) { o0[r] *= alpha; o1[r] *= alpha; }

            // P stays in-lane: k-slot permutation slot(g*8+j) <-> kv=(j>>2)*16+g*4+(j&3)
            union { bf16_t h[8]; bf16x8 v; } pb0, pb1;
#pragma unroll
            for (int r = 0; r < 4; ++r) {
                pb0.h[r]   = (bf16_t)p[0][r];
                pb0.h[4+r] = (bf16_t)p[1][r];
                pb1.h[r]   = (bf16_t)p[2][r];
                pb1.h[4+r] = (bf16_t)p[3][r];
            }
            // V^T A-frags under the same slot permutation (2x b64 each)
            const bf16_t* vb = &Vts[cur][0];
            bf16x4 v00a = *(const bf16x4*)(vb + l15*72 + g*4);
            bf16x4 v00b = *(const bf16x4*)(vb + l15*72 + 16 + g*4);
            bf16x4 v01a = *(const bf16x4*)(vb + l15*72 + 32 + g*4);
            bf16x4 v01b = *(const bf16x4*)(vb + l15*72 + 48 + g*4);
            bf16x4 v10a = *(const bf16x4*)(vb + (16+l15)*72 + g*4);
            bf16x4 v10b = *(const bf16x4*)(vb + (16+l15)*72 + 16 + g*4);
            bf16x4 v11a = *(const bf16x4*)(vb + (16+l15)*72 + 32 + g*4);
            bf16x4 v11b = *(const bf16x4*)(vb + (16+l15)*72 + 48 + g*4);
            // O^T = V^T · P^T : lane (l15,g) accumulates q=l15, d=g*4+r (+16)
            o0 = __builtin_amdgcn_mfma_f32_16x16x32_bf16(
                __builtin_shufflevector(v00a, v00b, 0,1,2,3,4,5,6,7), pb0.v, o0, 0,0,0);
            o0 = __builtin_amdgcn_mfma_f32_16x16x32_bf16(
                __builtin_shufflevector(v01a, v01b, 0,1,2,3,4,5,6,7), pb1.v, o0, 0,0,0);
            o1 = __builtin_amdgcn_mfma_f32_16x16x32_bf16(
                __builtin_shufflevector(v10a, v10b, 0,1,2,3,4,5,6,7), pb0.v, o1, 0,0,0);
            o1 = __builtin_amdgcn_mfma_f32_16x16x32_bf16(
                __builtin_shufflevector(v11a, v11b, 0,1,2,3,4,5,6,7), pb1.v, o1, 0,0,0);

            // write next tile into the other buffer (no barrier needed here)
            if (j < qt) {
                *(bf16x8*)(&Ks[cur^1][kr*40 + kc]) = kreg;
#pragma unroll
                for (int e = 0; e < 8; ++e) Vts[cur^1][(vc+e)*72 + vr] = vreg[e];
            }
        }
        __syncthreads();   // last-tile readers done before next half restages

        // epilogue: lane (l15,g) holds O[q][d=g*4+r] and [d=16+g*4+r]
        const float inv = 1.f / l;
        const int q = n0 + wv*16 + l15;
        union { bf16_t h[4]; uint2 u; } w0, w1;
#pragma unroll
        for (int r = 0; r < 4; ++r) {
            w0.h[r] = (bf16_t)(o0[r]*inv);
            w1.h[r] = (bf16_t)(o1[r]*inv);
        }
        const size_t base = ((size_t)bb*SEQ + q)*WDIM + hh*ATTD;
        *(uint2*)(ATTo + base + g*4)      = w0.u;
        *(uint2*)(ATTo + base + 16 + g*4) = w1.u;
    }
}

// ---------------- launch ----------------
extern "C" void kernel_launch(void* const* d_in, const int* in_sizes, int n_in,
                              void* d_out, int out_size, void* d_ws, size_t ws_size,
                              hipStream_t stream) {
    const float* q_in = (const float*)d_in[0];
    const float* k_in = (const float*)d_in[1];
    const float* v_in = (const float*)d_in[2];
    const float* Wq = (const float*)d_in[3];
    const float* bq = (const float*)d_in[4];
    const float* Wk = (const float*)d_in[5];
    const float* bk = (const float*)d_in[6];
    const float* Wv = (const float*)d_in[7];
    const float* bv = (const float*)d_in[8];
    const float* Wo = (const float*)d_in[9];
    const float* bo = (const float*)d_in[10];

    bf16_t* QKVh = (bf16_t*)d_ws;              // 3 * 8.4 MB
    bf16_t* ATTo = QKVh + 3*HBSZ;              // 8.4 MB

    gemm_kernel<0><<<dim3(2,128,3), 256, 0, stream>>>(
        q_in, k_in, v_in, Wq, Wk, Wv, bq, bk, bv, QKVh);
    attn_kernel<<<dim3(16,64), 256, 0, stream>>>(
        QKVh, QKVh + HBSZ, QKVh + 2*HBSZ, ATTo);
    gemm_kernel<1><<<dim3(2,128,1), 256, 0, stream>>>(
        ATTo, nullptr, nullptr, Wo, nullptr, nullptr, bo, nullptr, nullptr, d_out);
}

// Round 6
// 106.079 us; speedup vs baseline: 2.3724x; 1.0433x over previous
//
#include <hip/hip_runtime.h>
#include <hip/hip_bf16.h>
#include <stdint.h>

typedef __bf16 bf16_t;
typedef __bf16 bf16x4 __attribute__((ext_vector_type(4)));
typedef __bf16 bf16x8 __attribute__((ext_vector_type(8)));
typedef float f32x4 __attribute__((ext_vector_type(4)));
typedef __attribute__((address_space(3))) bf16_t* ldsp;

#define HEADS 8
#define ATTD 32
#define NBATCH 8
#define SEQ 2048
#define DIN 256
#define WDIM 256
#define MTOT (NBATCH*SEQ)          // 16384
#define HBSZ ((size_t)MTOT*WDIM)   // elems of ONE split-head tensor [64][2048][32]
// (1/sqrt(32)) * log2(e) — folded into Q during the QKV GEMM epilogue
#define SCALE_L2E 0.25503322964704155f

// ---------------- GEMM: out[m,o] = X[m,:] . W[o,:] + bias[o] ----------------
// MODE 0: X = f32 (q/k/v inputs, selected by z), W = f32; out bf16 split-head
//         [(o>>5)*MTOT + m][o&31] at outbase + z*HBSZ; z==0 scaled by SCALE_L2E.
// MODE 1: X = bf16 (ATTo), W = f32 (Wo); out f32 plain [m][o]
template<int MODE>
__global__ __launch_bounds__(256) void gemm_kernel(
    const void* __restrict__ X0, const void* __restrict__ X1,
    const void* __restrict__ X2,
    const float* __restrict__ W0, const float* __restrict__ W1,
    const float* __restrict__ W2,
    const float* __restrict__ b0, const float* __restrict__ b1,
    const float* __restrict__ b2, void* __restrict__ outbase)
{
    __shared__ bf16_t As[128*64];
    __shared__ bf16_t Bs[128*64];

    const int tid = threadIdx.x;
    const int z   = blockIdx.z;
    const int m0  = blockIdx.y * 128;
    const int n0  = blockIdx.x * 128;
    const void*  Xin  = (z == 0) ? X0 : (z == 1) ? X1 : X2;
    const float* Wf   = (z == 0) ? W0 : (z == 1) ? W1 : W2;
    const float* bias = (z == 0) ? b0 : (z == 1) ? b1 : b2;

    const int wv = tid >> 6, ln = tid & 63, g = ln >> 4, l15 = ln & 15;
    const int wm = wv >> 1, wn = wv & 1;

    f32x4 acc[4][4];
#pragma unroll
    for (int i = 0; i < 4; ++i)
#pragma unroll
        for (int j = 0; j < 4; ++j) acc[i][j] = (f32x4){0.f,0.f,0.f,0.f};

    for (int kt = 0; kt < DIN/64; ++kt) {
        if (kt) __syncthreads();
#pragma unroll
        for (int iss = 0; iss < 4; ++iss) {
            int chunk = iss*256 + tid;
            int row = chunk >> 3, c8 = (chunk & 7) * 8;
            union { bf16_t h[8]; bf16x8 v; } av, bvv;
            if (MODE == 0) {
                const float* A = (const float*)Xin;
                float4 a0 = *(const float4*)(A + (size_t)(m0+row)*DIN + kt*64 + c8);
                float4 a1 = *(const float4*)(A + (size_t)(m0+row)*DIN + kt*64 + c8 + 4);
                av.h[0]=(bf16_t)a0.x; av.h[1]=(bf16_t)a0.y; av.h[2]=(bf16_t)a0.z; av.h[3]=(bf16_t)a0.w;
                av.h[4]=(bf16_t)a1.x; av.h[5]=(bf16_t)a1.y; av.h[6]=(bf16_t)a1.z; av.h[7]=(bf16_t)a1.w;
            } else {
                av.v = *(const bf16x8*)((const bf16_t*)Xin + (size_t)(m0+row)*DIN + kt*64 + c8);
            }
            float4 w0 = *(const float4*)(Wf + (size_t)(n0+row)*DIN + kt*64 + c8);
            float4 w1 = *(const float4*)(Wf + (size_t)(n0+row)*DIN + kt*64 + c8 + 4);
            bvv.h[0]=(bf16_t)w0.x; bvv.h[1]=(bf16_t)w0.y; bvv.h[2]=(bf16_t)w0.z; bvv.h[3]=(bf16_t)w0.w;
            bvv.h[4]=(bf16_t)w1.x; bvv.h[5]=(bf16_t)w1.y; bvv.h[6]=(bf16_t)w1.z; bvv.h[7]=(bf16_t)w1.w;
            *(bf16x8*)(As + chunk*8) = av.v;
            *(bf16x8*)(Bs + chunk*8) = bvv.v;
        }
        __syncthreads();
#pragma unroll
        for (int kk = 0; kk < 2; ++kk) {
            bf16x8 af[4], bfr[4];
#pragma unroll
            for (int i = 0; i < 4; ++i)
                af[i] = *(const bf16x8*)(As + (wm*64 + i*16 + l15)*64 + kk*32 + g*8);
#pragma unroll
            for (int j = 0; j < 4; ++j)
                bfr[j] = *(const bf16x8*)(Bs + (wn*64 + j*16 + l15)*64 + kk*32 + g*8);
#pragma unroll
            for (int i = 0; i < 4; ++i)
#pragma unroll
                for (int j = 0; j < 4; ++j)
                    acc[i][j] = __builtin_amdgcn_mfma_f32_16x16x32_bf16(
                        af[i], bfr[j], acc[i][j], 0, 0, 0);
        }
    }

    // epilogue: C/D layout col = l15, row = g*4 + r
#pragma unroll
    for (int i = 0; i < 4; ++i) {
        int m = m0 + wm*64 + i*16 + g*4;
#pragma unroll
        for (int j = 0; j < 4; ++j) {
            int o = n0 + wn*64 + j*16 + l15;
            float bb = bias[o];
#pragma unroll
            for (int r = 0; r < 4; ++r) {
                float val = acc[i][j][r] + bb;
                if (MODE == 0) {
                    if (z == 0) val *= SCALE_L2E;   // fold softmax scale into Q
                    bf16_t* out = (bf16_t*)outbase + (size_t)z * HBSZ;
                    out[((size_t)(o >> 5) * MTOT + (m + r)) * ATTD + (o & 31)] = (bf16_t)val;
                } else {
                    ((float*)outbase)[(size_t)(m + r) * WDIM + o] = val;
                }
            }
        }
    }
}

// ---------------- flash attention (swapped QK^T, in-reg softmax, tr-read V) --
// Qh/Kh/Vh: [64][2048][32] bf16 (bh = h*8 + b); Q pre-scaled by SCALE_L2E.
// ATTo: [b][n][h*32+d] bf16.
// Block: 2 q-tiles {qtx, 31-qtx} x 64 rows (uniform 33 kv-tiles). Wave wv owns
// q rows wv*16..+15; lane (l15,g): q = l15.
// V LDS layout: subtiled [kb=kv>>2][db=d>>4][kv&3][d&15] (128B subtiles) so
// the PV A-fragment (V^T) comes from ds_read_b64_tr_b16 with const offsets.
__global__ __launch_bounds__(256) void attn_kernel(
    const bf16_t* __restrict__ Qh, const bf16_t* __restrict__ Kh,
    const bf16_t* __restrict__ Vh, bf16_t* __restrict__ ATTo)
{
    __shared__ __align__(1024) bf16_t Ks[2][64*40];   // K tile [kv][d], stride 40
    __shared__ __align__(1024) bf16_t Vsub[2][2048];  // V subtiled, 4KB/buf

    const int qtx = blockIdx.x;
    const int bh  = blockIdx.y;
    const int hh = bh >> 3, bb = bh & 7;
    const int tid = threadIdx.x;
    const int wv = tid >> 6, ln = tid & 63, g = ln >> 4, l15 = ln & 15;

    const int kr = tid >> 2, kc = (tid & 3) * 8;   // K & V staging: 4 thr/row
    // V subtiled write position (elements): kb=kr>>2, rr=kr&3, db=oct>>1, cc=(oct&1)*8
    const int vdst = ((kr >> 2) * 2 + ((tid & 3) >> 1)) * 64 + (kr & 3) * 16 + (tid & 1) * 8;
    const f32x4 zero4 = {0.f,0.f,0.f,0.f};
    const size_t bhs = (size_t)bh * SEQ;

    for (int half = 0; half < 2; ++half) {
        const int qt = half ? (31 - qtx) : qtx;
        const int n0 = qt * 64;
        const bf16x8 qfrag = *(const bf16x8*)(Qh + (bhs + n0 + wv*16 + l15)*ATTD + g*8);
        f32x4 o0 = zero4, o1 = zero4;
        float m = -1e30f, l = 0.f;

        // prologue: stage tile 0 into buf0
        bf16x8 kreg = *(const bf16x8*)(Kh + (bhs + kr)*ATTD + kc);
        bf16x8 vreg = *(const bf16x8*)(Vh + (bhs + kr)*ATTD + kc);
        __syncthreads();   // previous half's readers done with LDS
        *(bf16x8*)(&Ks[0][kr*40 + kc]) = kreg;
        *(bf16x8*)(&Vsub[0][vdst]) = vreg;

        for (int j = 0; j <= qt; ++j) {
            const int cur = j & 1;
            // issue next tile's loads early (clamped reload on last iter)
            const int jn = (j < qt) ? (j + 1) : j;
            kreg = *(const bf16x8*)(Kh + (bhs + jn*64 + kr)*ATTD + kc);
            vreg = *(const bf16x8*)(Vh + (bhs + jn*64 + kr)*ATTD + kc);
            __syncthreads();   // buf[cur] fully staged; prev buf reads done

            // S^T = K·Q^T : lane (l15,g) gets q=l15, kv = c*16 + g*4 + r
            f32x4 s[4];
#pragma unroll
            for (int c = 0; c < 4; ++c) {
                bf16x8 kf = *(const bf16x8*)(&Ks[cur][(c*16 + l15)*40 + g*8]);
                s[c] = __builtin_amdgcn_mfma_f32_16x16x32_bf16(kf, qfrag, zero4, 0, 0, 0);
            }
            if (j == qt) {   // causal mask on diagonal tile
                const int ql = wv*16 + l15;
#pragma unroll
                for (int c = 0; c < 4; ++c)
#pragma unroll
                    for (int r = 0; r < 4; ++r)
                        if (c*16 + g*4 + r > ql) s[c][r] = -1e30f;
            }
            // row max: max3-friendly tree, then 2 cross-group shuffles
            float t0 = fmaxf(fmaxf(s[0][0], s[0][1]), s[0][2]);
            float t1 = fmaxf(fmaxf(s[0][3], s[1][0]), s[1][1]);
            float t2 = fmaxf(fmaxf(s[1][2], s[1][3]), s[2][0]);
            float t3 = fmaxf(fmaxf(s[2][1], s[2][2]), s[2][3]);
            float t4 = fmaxf(fmaxf(s[3][0], s[3][1]), s[3][2]);
            float pmax = fmaxf(fmaxf(fmaxf(t0, t1), fmaxf(t2, t3)),
                               fmaxf(t4, s[3][3]));
            pmax = fmaxf(pmax, __shfl_xor(pmax, 16));
            pmax = fmaxf(pmax, __shfl_xor(pmax, 32));
            // defer-max with THR=0: alpha==1 exactly when pmax<=m -> skip is exact
            if (!__all(pmax <= m)) {
                const float mnew = fmaxf(m, pmax);
                const float alpha = exp2f(m - mnew);
                m = mnew;
                l *= alpha;
#pragma unroll
                for (int r = 0; r < 4; ++r) { o0[r] *= alpha; o1[r] *= alpha; }
            }
            float p[4][4];
            float rsum = 0.f;
#pragma unroll
            for (int c = 0; c < 4; ++c)
#pragma unroll
                for (int r = 0; r < 4; ++r) {
                    p[c][r] = exp2f(s[c][r] - m);
                    rsum += p[c][r];
                }
            rsum += __shfl_xor(rsum, 16);
            rsum += __shfl_xor(rsum, 32);
            l += rsum;

            // V^T A-fragments via HW transpose read: one addr reg, const offsets.
            // addr byte = g*256 + l15*8 (+offset): subtile (kb*2+db)*128, col l15.
            ldsp va = (ldsp)&Vsub[cur][0] + g*128 + l15*4;
            bf16x4 t00, t01, t02, t03, t10, t11, t12, t13;
            asm volatile("ds_read_b64_tr_b16 %0, %1 offset:0"    : "=v"(t00) : "v"(va));
            asm volatile("ds_read_b64_tr_b16 %0, %1 offset:1024" : "=v"(t01) : "v"(va));
            asm volatile("ds_read_b64_tr_b16 %0, %1 offset:2048" : "=v"(t02) : "v"(va));
            asm volatile("ds_read_b64_tr_b16 %0, %1 offset:3072" : "=v"(t03) : "v"(va));
            asm volatile("ds_read_b64_tr_b16 %0, %1 offset:128"  : "=v"(t10) : "v"(va));
            asm volatile("ds_read_b64_tr_b16 %0, %1 offset:1152" : "=v"(t11) : "v"(va));
            asm volatile("ds_read_b64_tr_b16 %0, %1 offset:2176" : "=v"(t12) : "v"(va));
            asm volatile("ds_read_b64_tr_b16 %0, %1 offset:3200" : "=v"(t13) : "v"(va));

            // P -> bf16, slot permutation slot(g*8+j) <-> kv=(j>>2)*16+g*4+(j&3)
            union { bf16_t h[8]; bf16x8 v; } pb0, pb1;
#pragma unroll
            for (int r = 0; r < 4; ++r) {
                pb0.h[r]   = (bf16_t)p[0][r];
                pb0.h[4+r] = (bf16_t)p[1][r];
                pb1.h[r]   = (bf16_t)p[2][r];
                pb1.h[4+r] = (bf16_t)p[3][r];
            }

            // my asm loads are invisible to the compiler's waitcnt tracking
            asm volatile("s_waitcnt lgkmcnt(0)" ::: "memory");
            __builtin_amdgcn_sched_barrier(0);

            // O^T = V^T · P^T : lane (l15,g): q=l15, d=g*4+r (o0) / 16+g*4+r (o1)
            o0 = __builtin_amdgcn_mfma_f32_16x16x32_bf16(
                __builtin_shufflevector(t00, t01, 0,1,2,3,4,5,6,7), pb0.v, o0, 0,0,0);
            o0 = __builtin_amdgcn_mfma_f32_16x16x32_bf16(
                __builtin_shufflevector(t02, t03, 0,1,2,3,4,5,6,7), pb1.v, o0, 0,0,0);
            o1 = __builtin_amdgcn_mfma_f32_16x16x32_bf16(
                __builtin_shufflevector(t10, t11, 0,1,2,3,4,5,6,7), pb0.v, o1, 0,0,0);
            o1 = __builtin_amdgcn_mfma_f32_16x16x32_bf16(
                __builtin_shufflevector(t12, t13, 0,1,2,3,4,5,6,7), pb1.v, o1, 0,0,0);

            // write next tile into the other buffer (no barrier needed here)
            if (j < qt) {
                *(bf16x8*)(&Ks[cur^1][kr*40 + kc]) = kreg;
                *(bf16x8*)(&Vsub[cur^1][vdst]) = vreg;
            }
        }
        __syncthreads();   // last-tile readers done before next half restages

        // epilogue: lane (l15,g) holds O[q][d=g*4+r] and [d=16+g*4+r]
        const float inv = 1.f / l;
        const int q = n0 + wv*16 + l15;
        union { bf16_t h[4]; uint2 u; } w0, w1;
#pragma unroll
        for (int r = 0; r < 4; ++r) {
            w0.h[r] = (bf16_t)(o0[r]*inv);
            w1.h[r] = (bf16_t)(o1[r]*inv);
        }
        const size_t base = ((size_t)bb*SEQ + q)*WDIM + hh*ATTD;
        *(uint2*)(ATTo + base + g*4)      = w0.u;
        *(uint2*)(ATTo + base + 16 + g*4) = w1.u;
    }
}

// ---------------- launch ----------------
extern "C" void kernel_launch(void* const* d_in, const int* in_sizes, int n_in,
                              void* d_out, int out_size, void* d_ws, size_t ws_size,
                              hipStream_t stream) {
    const float* q_in = (const float*)d_in[0];
    const float* k_in = (const float*)d_in[1];
    const float* v_in = (const float*)d_in[2];
    const float* Wq = (const float*)d_in[3];
    const float* bq = (const float*)d_in[4];
    const float* Wk = (const float*)d_in[5];
    const float* bk = (const float*)d_in[6];
    const float* Wv = (const float*)d_in[7];
    const float* bv = (const float*)d_in[8];
    const float* Wo = (const float*)d_in[9];
    const float* bo = (const float*)d_in[10];

    bf16_t* QKVh = (bf16_t*)d_ws;              // 3 * 8.4 MB
    bf16_t* ATTo = QKVh + 3*HBSZ;              // 8.4 MB

    gemm_kernel<0><<<dim3(2,128,3), 256, 0, stream>>>(
        q_in, k_in, v_in, Wq, Wk, Wv, bq, bk, bv, QKVh);
    attn_kernel<<<dim3(16,64), 256, 0, stream>>>(
        QKVh, QKVh + HBSZ, QKVh + 2*HBSZ, ATTo);
    gemm_kernel<1><<<dim3(2,128,1), 256, 0, stream>>>(
        ATTo, nullptr, nullptr, Wo, nullptr, nullptr, bo, nullptr, nullptr, d_out);
}